// Round 13
// baseline (176.072 us; speedup 1.0000x reference)
//
#include <hip/hip_runtime.h>
#include <hip/hip_bf16.h>
#include <math.h>

// Problem constants (match reference setup_inputs)
#define B_SZ   2
#define N_SEQ  2048
#define C_DIM  1024
#define H_NUM  16
#define D_HEAD 64
#define M_ROWS (B_SZ * N_SEQ)   // 4096
#define QKV_N  (3 * C_DIM)      // 3072

typedef __attribute__((ext_vector_type(8))) short  bf16x8;
typedef __attribute__((ext_vector_type(4))) float  floatx4;

// fp32 -> bf16 bits, round-to-nearest-even
static __device__ __forceinline__ unsigned short f2bf(float x) {
    unsigned int u = __float_as_uint(x);
    u = (u + 0x7FFFu + ((u >> 16) & 1u)) >> 16;
    return (unsigned short)u;
}
// RNE-rounded bits kept in the high halfword (for pair packing via v_perm)
static __device__ __forceinline__ unsigned int f2bf_hi(float x) {
    unsigned int u = __float_as_uint(x);
    return u + 0x7FFFu + ((u >> 16) & 1u);
}
// pack (lo=a, hi=b) as two RNE bf16 in one u32
#if __has_builtin(__builtin_amdgcn_cvt_pk_bf16_f32)
typedef __bf16 bf16_2 __attribute__((ext_vector_type(2)));
static __device__ __forceinline__ unsigned int pkbf(float a, float b) {
    union { bf16_2 v; unsigned int u; } c;
    c.v = __builtin_amdgcn_cvt_pk_bf16_f32(a, b);
    return c.u;
}
#else
static __device__ __forceinline__ unsigned int pkbf(float a, float b) {
    return __builtin_amdgcn_perm(f2bf_hi(b), f2bf_hi(a), 0x07060302u);
}
#endif

#if __has_builtin(__builtin_amdgcn_exp2f)
#define EXP2F(x) __builtin_amdgcn_exp2f(x)
#else
#define EXP2F(x) exp2f(x)
#endif

#define GLP(p) ((const __attribute__((address_space(1))) void*)(p))
#define LDP(p) ((__attribute__((address_space(3))) void*)(p))

#define CEXP 0.18033688011112042f   // 0.125 * log2(e)

// ---------------------------------------------------------------------------
// Fused prep (1 launch): blocks [0,4096) convert x to bf16;
// [4096,4864) transpose-convert w_qkv; [4864,5120) transpose-convert w_proj.
// ---------------------------------------------------------------------------
__global__ __launch_bounds__(256)
void prep_fused(const float* __restrict__ x,      unsigned short* __restrict__ xb,
                const float* __restrict__ w_qkv,  unsigned short* __restrict__ wqkvT,
                const float* __restrict__ w_proj, unsigned short* __restrict__ wprojT)
{
    __shared__ unsigned short t[64][72];
    const int bid = blockIdx.x;
    const int tid = threadIdx.x;

    if (bid < 4096) {                        // x -> bf16 (exactly 1M float4 groups)
        const int i = bid * 256 + tid;
        float4 v = ((const float4*)x)[i];
        ushort4 p;
        p.x = f2bf(v.x); p.y = f2bf(v.y); p.z = f2bf(v.z); p.w = f2bf(v.w);
        ((ushort4*)xb)[i] = p;
        return;
    }

    const float* W;
    unsigned short* WT;
    int N, tt;
    if (bid < 4096 + 768) { W = w_qkv;  WT = wqkvT;  N = QKV_N; tt = bid - 4096; }
    else                  { W = w_proj; WT = wprojT; N = C_DIM; tt = bid - 4864; }
    const int ntiles = N / 64;
    const int n0 = (tt % ntiles) * 64;
    const int k0 = (tt / ntiles) * 64;
    const int K  = C_DIM;

    const int tc = tid & 15;
    const int tr = tid >> 4;
    #pragma unroll
    for (int p = 0; p < 4; ++p) {
        const int r = tr + p * 16;
        float4 v = *(const float4*)&W[(size_t)(k0 + r) * N + n0 + tc * 4];
        ushort4 pk;
        pk.x = f2bf(v.x); pk.y = f2bf(v.y); pk.z = f2bf(v.z); pk.w = f2bf(v.w);
        *(ushort4*)&t[r][tc * 4] = pk;
    }
    __syncthreads();

    const int n  = tid >> 2;
    const int c0 = (tid & 3) * 16;
    unsigned short tmp[16];
    #pragma unroll
    for (int i = 0; i < 16; ++i) tmp[i] = t[c0 + i][n];
    *(uint4*)&WT[(size_t)(n0 + n) * K + k0 + c0]     = *(uint4*)&tmp[0];
    *(uint4*)&WT[(size_t)(n0 + n) * K + k0 + c0 + 8] = *(uint4*)&tmp[8];
}

// ---------------------------------------------------------------------------
// QKV GEMM -- R16 geometry (256x192, counted-vmcnt pipeline, 256 blocks =
// 1/CU) + R18 LDS-transpose epilogue + R19 DEFERRED CLUSTER-2 (T15 at the
// 256-reg budget). Tile t's afh+bfr (56 regs) stay live across the boundary
// barrier; cluster-2 of t-1 executes as a pure-register 24-MFMA block at the
// top of iteration t, right after tile t's 14 frag reads are issued -- the
// barrier-wake + ds_read latency is covered by the MFMA pipe instead of
// being serial. Barriers/buffer lifetimes/staging/vmcnt identical to the
// 4x-validated template. Deferred inputs were lgkm-drained at t-1's
// mid-barrier; register-only MFMAs are immune to rule-18 reordering hazards.
// Peak liveness ~205 < 256 (2 waves/SIMD).
// ---------------------------------------------------------------------------
__global__ __launch_bounds__(512, 2)
void gemm_qkv(const unsigned short* __restrict__ A,   // xb [4096][1024]
              const unsigned short* __restrict__ BT,  // wqkvT [3072][1024]
              unsigned short* __restrict__ qbuf,
              unsigned short* __restrict__ kbuf,
              unsigned short* __restrict__ vbuf)
{
    extern __shared__ unsigned short lds2[];     // 112 KB
    unsigned short* AsB = lds2;                  // [2][256*64] = 32768 ushorts
    unsigned short* BsB = lds2 + 32768;          // [2][192*64] = 24576 ushorts

    const int K = C_DIM;
    const int tid  = threadIdx.x;
    const int lane = tid & 63;
    const int wave = tid >> 6;        // 0..7
    const int wm2  = wave >> 2;       // 0..1  M-half (128 rows)
    const int wn4  = wave & 3;        // 0..3  N-quarter (48 cols)
    const int l15  = lane & 15;
    const int lq   = lane >> 4;
    const int e7   = l15 & 7;

    // grid 256 = 16(M) x 16(N); bijective XCD swizzle (32 blocks per XCD)
    const int bid = blockIdx.x;                  // 0..255
    const int g   = (bid & 7) * 32 + (bid >> 3); // 0..255
    const int bm  = (g & 15) * 256;
    const int bn  = (g >> 4) * 192;

    // staging: 7 issues per K-tile (4 A + 3 B), each 512 thr x 16B = 8 KB.
    // issue i covers rows i*64 + srow; swizzle issue-invariant (64 % 8 == 0).
    const int srow = tid >> 3;                       // 0..63
    const int gso  = ((tid & 7) ^ (srow & 7)) * 8;   // logical col chunk

    const unsigned short* ga = A  + (size_t)(bm + srow) * K + gso;
    const unsigned short* gb = BT + (size_t)(bn + srow) * K + gso;

    floatx4 acc[8][3];
    #pragma unroll
    for (int i = 0; i < 8; ++i)
        #pragma unroll
        for (int j = 0; j < 3; ++j) acc[i][j] = (floatx4){0.f, 0.f, 0.f, 0.f};

#define QKV_STAGE(t_, buf_)                                                    \
    {                                                                          \
        unsigned short* Ad_ = AsB + (buf_) * 16384;                            \
        unsigned short* Bd_ = BsB + (buf_) * 12288;                            \
        _Pragma("unroll")                                                      \
        for (int i_ = 0; i_ < 4; ++i_)                                         \
            __builtin_amdgcn_global_load_lds(                                  \
                GLP(ga + (size_t)i_ * 64 * K + (t_) * 64),                     \
                LDP(Ad_ + i_ * 4096 + tid * 8), 16, 0, 0);                     \
        _Pragma("unroll")                                                      \
        for (int i_ = 0; i_ < 3; ++i_)                                         \
            __builtin_amdgcn_global_load_lds(                                  \
                GLP(gb + (size_t)i_ * 64 * K + (t_) * 64),                     \
                LDP(Bd_ + i_ * 4096 + tid * 8), 16, 0, 0);                     \
    }

    // prologue: stage tiles 0 and 1; wait tile 0 (7 of 14 loads) only.
    QKV_STAGE(0, 0);
    QKV_STAGE(1, 1);
    asm volatile("s_waitcnt vmcnt(7)\ns_barrier" ::: "memory");

    // deferred-cluster pipeline registers (tile t-1's A-high + B frags)
    bf16x8 afhP[2][4], bfrP[2][3];

    for (int t = 0; t < 16; ++t) {
        const int cur = t & 1;
        const unsigned short* Ac = AsB + cur * 16384;
        const unsigned short* Bc = BsB + cur * 12288;

        // frag reads: A-low half (m-frags 0..3) + all B  (issued first)
        bf16x8 afl[2][4], bfr[2][3];
        #pragma unroll
        for (int kc = 0; kc < 2; ++kc) {
            #pragma unroll
            for (int mt = 0; mt < 4; ++mt)
                afl[kc][mt] = *(const bf16x8*)&Ac[(wm2 * 128 + mt * 16 + l15) * 64
                                                  + (((kc * 4 + lq) ^ e7) * 8)];
            #pragma unroll
            for (int nt = 0; nt < 3; ++nt)
                bfr[kc][nt] = *(const bf16x8*)&Bc[(wn4 * 48 + nt * 16 + l15) * 64
                                                  + (((kc * 4 + lq) ^ e7) * 8)];
        }

        // DEFERRED cluster-2 of tile t-1: pure-register MFMAs issue while
        // this tile's ds_reads are in flight (covers read + barrier latency).
        if (t) {
            __builtin_amdgcn_s_setprio(1);
            #pragma unroll
            for (int kc = 0; kc < 2; ++kc)
                #pragma unroll
                for (int mt = 0; mt < 4; ++mt)
                    #pragma unroll
                    for (int nt = 0; nt < 3; ++nt)
                        acc[4 + mt][nt] = __builtin_amdgcn_mfma_f32_16x16x32_bf16(
                            afhP[kc][mt], bfrP[kc][nt], acc[4 + mt][nt], 0, 0, 0);
            __builtin_amdgcn_s_setprio(0);
        }

        // MFMA cluster 1 (m-frags 0..3 of tile t)
        __builtin_amdgcn_s_setprio(1);
        #pragma unroll
        for (int kc = 0; kc < 2; ++kc)
            #pragma unroll
            for (int mt = 0; mt < 4; ++mt)
                #pragma unroll
                for (int nt = 0; nt < 3; ++nt)
                    acc[mt][nt] = __builtin_amdgcn_mfma_f32_16x16x32_bf16(
                        afl[kc][mt], bfr[kc][nt], acc[mt][nt], 0, 0, 0);
        __builtin_amdgcn_s_setprio(0);

        // frag reads: A-high half (m-frags 4..7) -- consumed NEXT iteration
        bf16x8 afh[2][4];
        #pragma unroll
        for (int kc = 0; kc < 2; ++kc)
            #pragma unroll
            for (int mt = 0; mt < 4; ++mt)
                afh[kc][mt] = *(const bf16x8*)&Ac[(wm2 * 128 + 64 + mt * 16 + l15) * 64
                                                  + (((kc * 4 + lq) ^ e7) * 8)];

        // all reads of buf[cur] are in regs after this -> buffer free
        asm volatile("s_waitcnt lgkmcnt(0)\ns_barrier" ::: "memory");

        // prefetch tile t+2 into the just-freed buffer (same parity)
        if (t < 14) QKV_STAGE(t + 2, cur);

        // carry tile t's cluster-2 inputs into the next iteration
        #pragma unroll
        for (int kc = 0; kc < 2; ++kc) {
            #pragma unroll
            for (int mt = 0; mt < 4; ++mt) afhP[kc][mt] = afh[kc][mt];
            #pragma unroll
            for (int nt = 0; nt < 3; ++nt) bfrP[kc][nt] = bfr[kc][nt];
        }

        // boundary: force tile t+1 complete, keep t+2's 7 loads in flight
        if (t < 14)       asm volatile("s_waitcnt vmcnt(7)\ns_barrier" ::: "memory");
        else if (t == 14) asm volatile("s_waitcnt vmcnt(0)\ns_barrier" ::: "memory");
        // t == 15: no boundary wait; drain + epilogue follow
    }
#undef QKV_STAGE

    // drain: cluster-2 of the final tile (register-only)
    {
        __builtin_amdgcn_s_setprio(1);
        #pragma unroll
        for (int kc = 0; kc < 2; ++kc)
            #pragma unroll
            for (int mt = 0; mt < 4; ++mt)
                #pragma unroll
                for (int nt = 0; nt < 3; ++nt)
                    acc[4 + mt][nt] = __builtin_amdgcn_mfma_f32_16x16x32_bf16(
                        afhP[kc][mt], bfrP[kc][nt], acc[4 + mt][nt], 0, 0, 0);
        __builtin_amdgcn_s_setprio(0);
    }

    // ---- R18 epilogue: LDS col-major transpose, then coalesced stores ----
    // Tc[192][256] bf16 col-major image, 96 KB (fits the 112 KB allocation).
    // Element index: cc*256 + (r ^ xr(cc)), xr(cc) = ((2cc + (cc>>3)) & 31) << 2.
    asm volatile("s_waitcnt lgkmcnt(0)\ns_barrier" ::: "memory");
    unsigned short* Tc = lds2;

    // write phase: each lane writes 24 x 8B (4 consecutive rows, one col)
    #pragma unroll
    for (int nt = 0; nt < 3; ++nt) {
        const int lc   = wn4 * 48 + nt * 16 + l15;     // local col 0..191
        const int gcol = bn + lc;                      // global col
        const float sc = ((gcol >> 10) == 0) ? CEXP : 1.0f;  // q pre-scale
        const int xr   = ((2 * lc + (lc >> 3)) & 31) << 2;
        #pragma unroll
        for (int mt = 0; mt < 8; ++mt) {
            const int r0 = wm2 * 128 + mt * 16 + lq * 4;     // aligned 4
            unsigned int* p = (unsigned int*)&Tc[lc * 256 + (r0 ^ xr)];
            p[0] = pkbf(acc[mt][nt][0] * sc, acc[mt][nt][1] * sc);
            p[1] = pkbf(acc[mt][nt][2] * sc, acc[mt][nt][3] * sc);
        }
    }
    asm volatile("s_waitcnt lgkmcnt(0)\ns_barrier" ::: "memory");

    // read + coalesced-store phase, per 64-col head chunk
    const int bq = bm >> 11;           // batch (uniform per block)
    const int nb = bm & 2047;          // row base within batch
    #pragma unroll
    for (int hc = 0; hc < 3; ++hc) {
        const int colg = bn + hc * 64;
        const int reg3 = colg >> 10;               // 0=q, 1=k, 2=v
        const int h    = (colg >> 6) & 15;
        if (reg3 < 2) {
            // dest: contiguous 256x64 bf16 block, row-major [n][d]
            unsigned short* dstb = (reg3 ? kbuf : qbuf)
                + ((size_t)(bq * H_NUM + h) * N_SEQ + nb) * D_HEAD;
            const int col0 = (tid & 7) * 8;        // 0..56
            const int row  = tid >> 3;             // 0..63
            #pragma unroll
            for (int rr = 0; rr < 4; ++rr) {
                const int r = row + rr * 64;       // 0..255
                union { unsigned short s[8]; uint4 v; } u;
                #pragma unroll
                for (int c = 0; c < 8; ++c) {
                    const int cc = hc * 64 + col0 + c;
                    const int xr = ((2 * cc + (cc >> 3)) & 31) << 2;
                    u.s[c] = Tc[cc * 256 + (r ^ xr)];
                }
                *(uint4*)&dstb[(size_t)r * D_HEAD + col0] = u.v;
            }
        } else {
            // dest: vbuf[(bq*16+h)*64 + d][ (n&~63) + fk(n&63) ]
            // inverse perm: source a(p) = (p&0x23)|((p&0x18)>>1)|((p&4)<<2);
            // 16B dest run p0..p0+7 -> two 8B source runs {ab..+3},{ab+16..+19}
            unsigned short* dstb = vbuf
                + (size_t)(bq * H_NUM + h) * D_HEAD * N_SEQ;
            const int d  = tid >> 3;               // 0..63
            const int p0 = (tid & 7) * 8;          // 0..56
            const int cc = hc * 64 + d;
            const int ab = (p0 & 0x23) | ((p0 & 0x18) >> 1) | ((p0 & 4) << 2);
            const int xr = ((2 * cc + (cc >> 3)) & 31) << 2;
            #pragma unroll
            for (int gg = 0; gg < 4; ++gg) {
                const int rb = gg * 64;
                ushort4 ra = *(ushort4*)&Tc[cc * 256 + ((rb + ab) ^ xr)];
                ushort4 rc = *(ushort4*)&Tc[cc * 256 + ((rb + ab + 16) ^ xr)];
                union { unsigned short s[8]; uint4 v; } u;
                u.s[0] = ra.x; u.s[1] = ra.y; u.s[2] = ra.z; u.s[3] = ra.w;
                u.s[4] = rc.x; u.s[5] = rc.y; u.s[6] = rc.z; u.s[7] = rc.w;
                *(uint4*)&dstb[(size_t)d * N_SEQ + nb + rb + p0] = u.v;
            }
        }
    }
}

// ---------------------------------------------------------------------------
// S^T-form bf16 MFMA flash attention, fixed-max softmax. R8 EXACT (measured
// best: 51.0 us): 8 waves/block (512 thr), waves split into 2 KEY-groups --
// grp0 (waves 0-3) even 64-key tiles, grp1 (waves 4-7) odd tiles, lockstep
// 128-key super-tiles. Fixed-max softmax => partial (O,l) over disjoint key
// sets add exactly; one LDS combine at the end.
// Grid = 512 blocks (2 blocks/CU, 16 waves/CU = 4 waves/SIMD).
// LDS: 4 K-tiles + 4 V-tiles = 64 KB, double-buffered at super-tile level.
// q pre-scaled by CEXP; S-acc init -8 folds the softmax shift.
// ---------------------------------------------------------------------------
__global__ __launch_bounds__(512, 4)
void attn_mfma(const unsigned short* __restrict__ qbuf,
               const unsigned short* __restrict__ kbuf,
               const unsigned short* __restrict__ vbuf,
               unsigned short* __restrict__ attnb)
{
    __shared__ unsigned short KsS[2][2][64 * 64];   // [pair][tile-in-pair] 32 KB
    __shared__ unsigned short VtS[2][2][64 * 64];   // 32 KB

    const int tid  = threadIdx.x;
    const int lane = tid & 63;
    const int wave = tid >> 6;           // 0..7
    const int grp  = wave >> 2;          // 0: even tiles, 1: odd tiles
    const int wrow = wave & 3;           // q-row group within block
    const int l15  = lane & 15;
    const int lq   = lane >> 4;
    const int e    = l15 & 7;

    // XCD swizzle: low 3 bits pick XCD; same bh stays in one XCD group
    const int bid  = blockIdx.x;                    // 0..511
    const int bh   = (bid & 7) * 4 + (bid >> 7);    // 0..31
    const int qblk = (bid >> 3) & 15;               // 0..15
    const int b    = bh >> 4;
    const int h    = bh & 15;
    const int q0   = qblk * 128 + wrow * 32;

    const unsigned short* khead = kbuf + (size_t)bh * N_SEQ * D_HEAD;
    const unsigned short* vhead = vbuf + (size_t)bh * D_HEAD * N_SEQ;

    // Q B-frags, 2 q-column blocks (q pre-scaled by CEXP at gemm_qkv)
    bf16x8 qf[2][2];   // [kchunk][qb]
    #pragma unroll
    for (int qb = 0; qb < 2; ++qb) {
        const unsigned short* qrow = qbuf
            + ((size_t)bh * N_SEQ + q0 + qb * 16 + l15) * D_HEAD + lq * 8;
        qf[0][qb] = *(const bf16x8*)qrow;
        qf[1][qb] = *(const bf16x8*)(qrow + 32);
    }

    floatx4 acc[4][2];
    #pragma unroll
    for (int dc = 0; dc < 4; ++dc)
        #pragma unroll
        for (int qb = 0; qb < 2; ++qb) acc[dc][qb] = (floatx4){0.f, 0.f, 0.f, 0.f};
    float lsum[2] = {0.f, 0.f};

    // staging: 512 threads x 16B = one full 8KB tile per issue.
    // row = tid>>3 (0..63), phys seg = tid&7, global col chunk = seg^(row&7)
    const int srow = tid >> 3;                        // 0..63
    const int gso  = ((tid & 7) ^ (srow & 7)) * 8;

    // prologue: stage super-tile 0 (key tiles 0,1) into pair 0
    #pragma unroll
    for (int i = 0; i < 2; ++i) {
        __builtin_amdgcn_global_load_lds(GLP(khead + (size_t)(i * 64 + srow) * 64 + gso),
                                         LDP(&KsS[0][i][tid * 8]), 16, 0, 0);
        __builtin_amdgcn_global_load_lds(GLP(vhead + (size_t)srow * N_SEQ + i * 64 + gso),
                                         LDP(&VtS[0][i][tid * 8]), 16, 0, 0);
    }

    for (int s = 0; s < N_SEQ / 128; ++s) {
        const int cur = s & 1;
        __syncthreads();   // drains DMA for pair cur; prior reads of cur^1 done

        if (s + 1 < N_SEQ / 128) {
            const int m1 = (s + 1) * 128;
            const int nx = cur ^ 1;
            #pragma unroll
            for (int i = 0; i < 2; ++i) {
                __builtin_amdgcn_global_load_lds(
                    GLP(khead + (size_t)(m1 + i * 64 + srow) * 64 + gso),
                    LDP(&KsS[nx][i][tid * 8]), 16, 0, 0);
                __builtin_amdgcn_global_load_lds(
                    GLP(vhead + (size_t)srow * N_SEQ + m1 + i * 64 + gso),
                    LDP(&VtS[nx][i][tid * 8]), 16, 0, 0);
            }
        }

        const unsigned short* Ksc = &KsS[cur][grp][0];
        const unsigned short* Vtc = &VtS[cur][grp][0];

        // S^T = K Q^T (acc init -8 folds the softmax shift); K frags shared
        // across both q-blocks.
        floatx4 st[4][2];
        #pragma unroll
        for (int t = 0; t < 4; ++t) {
            bf16x8 k0 = *(const bf16x8*)&Ksc[(t * 16 + l15) * 64 + ((lq ^ e) * 8)];
            bf16x8 k1 = *(const bf16x8*)&Ksc[(t * 16 + l15) * 64 + (((4 + lq) ^ e) * 8)];
            #pragma unroll
            for (int qb = 0; qb < 2; ++qb) {
                floatx4 sv = (floatx4){-8.f, -8.f, -8.f, -8.f};
                sv = __builtin_amdgcn_mfma_f32_16x16x32_bf16(k0, qf[0][qb], sv, 0, 0, 0);
                sv = __builtin_amdgcn_mfma_f32_16x16x32_bf16(k1, qf[1][qb], sv, 0, 0, 0);
                st[t][qb] = sv;
            }
        }

        // fixed-max softmax: p = 2^st; packed RNE bf16 pairs
        bf16x8 pf[2][2];   // [kchunk][qb]
        #pragma unroll
        for (int qb = 0; qb < 2; ++qb) {
            unsigned int pk[8];
            float la = 0.f;
            #pragma unroll
            for (int t = 0; t < 4; ++t) {
                float p0 = EXP2F(st[t][qb][0]);
                float p1 = EXP2F(st[t][qb][1]);
                float p2 = EXP2F(st[t][qb][2]);
                float p3 = EXP2F(st[t][qb][3]);
                la += (p0 + p1) + (p2 + p3);
                pk[t * 2]     = pkbf(p0, p1);
                pk[t * 2 + 1] = pkbf(p2, p3);
            }
            lsum[qb] += la;
            union { uint4 u; bf16x8 v; } c0, c1;
            c0.u = make_uint4(pk[0], pk[1], pk[2], pk[3]);
            c1.u = make_uint4(pk[4], pk[5], pk[6], pk[7]);
            pf[0][qb] = c0.v;
            pf[1][qb] = c1.v;
        }

        // O^T += V^T P^T; V frags shared across both q-blocks
        #pragma unroll
        for (int dc = 0; dc < 4; ++dc) {
            bf16x8 v0 = *(const bf16x8*)&Vtc[(dc * 16 + l15) * 64 + ((lq ^ e) * 8)];
            bf16x8 v1 = *(const bf16x8*)&Vtc[(dc * 16 + l15) * 64 + (((4 + lq) ^ e) * 8)];
            #pragma unroll
            for (int qb = 0; qb < 2; ++qb) {
                acc[dc][qb] = __builtin_amdgcn_mfma_f32_16x16x32_bf16(
                    v0, pf[0][qb], acc[dc][qb], 0, 0, 0);
                acc[dc][qb] = __builtin_amdgcn_mfma_f32_16x16x32_bf16(
                    v1, pf[1][qb], acc[dc][qb], 0, 0, 0);
            }
        }
    }

    // cross-group combine (disjoint key sets => partials add exactly).
    // grp1 writes acc (32 f32/lane, XOR-swizzled: conflict-free) + lsum to
    // LDS; grp0 adds, normalizes, stores.
    __syncthreads();
    float* smA = (float*)&KsS[0][0][0];   // 32 KB: 4 waves x 64 lanes x 32 f32
    float* smL = (float*)&VtS[0][0][0];   // lsum partials
    const int li = wrow * 64 + lane;
    if (grp) {
        float* p = smA + li * 32;
        #pragma unroll
        for (int dc = 0; dc < 4; ++dc)
            #pragma unroll
            for (int qb = 0; qb < 2; ++qb)
                #pragma unroll
                for (int r = 0; r < 4; ++r)
                    p[(dc * 8 + qb * 4 + r) ^ (lane & 31)] = acc[dc][qb][r];
        smL[li * 2]     = lsum[0];
        smL[li * 2 + 1] = lsum[1];
    }
    __syncthreads();
    if (grp) return;

    {
        const float* p = smA + li * 32;
        #pragma unroll
        for (int dc = 0; dc < 4; ++dc)
            #pragma unroll
            for (int qb = 0; qb < 2; ++qb)
                #pragma unroll
                for (int r = 0; r < 4; ++r)
                    acc[dc][qb][r] += p[(dc * 8 + qb * 4 + r) ^ (lane & 31)];
        lsum[0] += smL[li * 2];
        lsum[1] += smL[li * 2 + 1];
    }

    // epilogue: reduce l across lq groups, normalize, store bf16
    #pragma unroll
    for (int qb = 0; qb < 2; ++qb) {
        float l = lsum[qb];
        l += __shfl_xor(l, 16, 64);
        l += __shfl_xor(l, 32, 64);
        const float inv = 1.f / l;
        const int q = q0 + qb * 16 + l15;
        unsigned short* orow = attnb + ((size_t)b * N_SEQ + q) * C_DIM + h * D_HEAD;
        #pragma unroll
        for (int dc = 0; dc < 4; ++dc) {
            ushort4 pkk;
            pkk.x = f2bf(acc[dc][qb][0] * inv);
            pkk.y = f2bf(acc[dc][qb][1] * inv);
            pkk.z = f2bf(acc[dc][qb][2] * inv);
            pkk.w = f2bf(acc[dc][qb][3] * inv);
            *(ushort4*)&orow[dc * 16 + lq * 4] = pkk;
        }
    }
}

// ---------------------------------------------------------------------------
// Output projection GEMM -- R17: counted-vmcnt pipeline port (same template
// as gemm_qkv R16). 256(M) x 64(N) tile, grid 16x16 = 256 blocks = 1/CU.
// 512 thr = 8 waves (2M x 4N), per-wave 128x16 output (acc[8], 32 regs).
// Staging 5 loads/K-tile (4 A + 1 B; B-tile 64x64 = one full 8KB issue);
// boundary vmcnt(5). LDS 80 KB (A 2x32 + B 2x8), padded to 96 KB request to
// pin exactly 1 block/CU. fp32 out + bias.
// ---------------------------------------------------------------------------
__global__ __launch_bounds__(512, 2)
void gemm_bt(const unsigned short* __restrict__ A,   // [M][K] bf16
             const unsigned short* __restrict__ BT,  // [N][K] bf16
             const float* __restrict__ bias,         // [N] fp32
             float* __restrict__ Cm,
             int M, int N, int K)
{
    extern __shared__ unsigned short ldsb[];     // 96 KB requested
    unsigned short* AsB = ldsb;                  // [2][256*64] = 32768 ushorts
    unsigned short* BsB = ldsb + 32768;          // [2][64*64]  = 8192 ushorts

    const int tid  = threadIdx.x;
    const int lane = tid & 63;
    const int wave = tid >> 6;        // 0..7
    const int wm2  = wave >> 2;       // 0..1  M-half (128 rows)
    const int wn4  = wave & 3;        // 0..3  N-quarter (16 cols)
    const int l15  = lane & 15;
    const int lq   = lane >> 4;
    const int e7   = l15 & 7;

    // grid 256 = 16(M) x 16(N); bijective XCD swizzle (32 blocks per XCD)
    const int bid = blockIdx.x;                  // 0..255
    const int g   = (bid & 7) * 32 + (bid >> 3); // 0..255
    const int bm  = (g & 15) * 256;
    const int bn  = (g >> 4) * 64;

    const int srow = tid >> 3;                       // 0..63
    const int gso  = ((tid & 7) ^ (srow & 7)) * 8;   // logical col chunk

    const unsigned short* ga = A  + (size_t)(bm + srow) * K + gso;
    const unsigned short* gb = BT + (size_t)(bn + srow) * K + gso;

    floatx4 acc[8];
    #pragma unroll
    for (int i = 0; i < 8; ++i) acc[i] = (floatx4){0.f, 0.f, 0.f, 0.f};

#define BT_STAGE(t_, buf_)                                                     \
    {                                                                          \
        unsigned short* Ad_ = AsB + (buf_) * 16384;                            \
        unsigned short* Bd_ = BsB + (buf_) * 4096;                             \
        _Pragma("unroll")                                                      \
        for (int i_ = 0; i_ < 4; ++i_)                                         \
            __builtin_amdgcn_global_load_lds(                                  \
                GLP(ga + (size_t)i_ * 64 * K + (t_) * 64),                     \
                LDP(Ad_ + i_ * 4096 + tid * 8), 16, 0, 0);                     \
        __builtin_amdgcn_global_load_lds(                                      \
            GLP(gb + (t_) * 64),                                               \
            LDP(Bd_ + tid * 8), 16, 0, 0);                                     \
    }

    // prologue: stage tiles 0 and 1; wait tile 0 (5 of 10 loads) only.
    BT_STAGE(0, 0);
    BT_STAGE(1, 1);
    asm volatile("s_waitcnt vmcnt(5)\ns_barrier" ::: "memory");

    for (int t = 0; t < 16; ++t) {
        const int cur = t & 1;
        const unsigned short* Ac = AsB + cur * 16384;
        const unsigned short* Bc = BsB + cur * 4096;

        // frag reads: A-low half (m-frags 0..3) + B
        bf16x8 afl[2][4], bfr[2];
        #pragma unroll
        for (int kc = 0; kc < 2; ++kc) {
            #pragma unroll
            for (int mt = 0; mt < 4; ++mt)
                afl[kc][mt] = *(const bf16x8*)&Ac[(wm2 * 128 + mt * 16 + l15) * 64
                                                  + (((kc * 4 + lq) ^ e7) * 8)];
            bfr[kc] = *(const bf16x8*)&Bc[(wn4 * 16 + l15) * 64
                                          + (((kc * 4 + lq) ^ e7) * 8)];
        }

        // MFMA cluster 1 (m-frags 0..3)
        __builtin_amdgcn_s_setprio(1);
        #pragma unroll
        for (int kc = 0; kc < 2; ++kc)
            #pragma unroll
            for (int mt = 0; mt < 4; ++mt)
                acc[mt] = __builtin_amdgcn_mfma_f32_16x16x32_bf16(
                    afl[kc][mt], bfr[kc], acc[mt], 0, 0, 0);
        __builtin_amdgcn_s_setprio(0);

        // frag reads: A-high half (m-frags 4..7)
        bf16x8 afh[2][4];
        #pragma unroll
        for (int kc = 0; kc < 2; ++kc)
            #pragma unroll
            for (int mt = 0; mt < 4; ++mt)
                afh[kc][mt] = *(const bf16x8*)&Ac[(wm2 * 128 + 64 + mt * 16 + l15) * 64
                                                  + (((kc * 4 + lq) ^ e7) * 8)];

        // all reads of buf[cur] are in regs after this -> buffer free
        asm volatile("s_waitcnt lgkmcnt(0)\ns_barrier" ::: "memory");

        // prefetch tile t+2 into the just-freed buffer (same parity)
        if (t < 14) BT_STAGE(t + 2, cur);

        // MFMA cluster 2 (m-frags 4..7)
        __builtin_amdgcn_s_setprio(1);
        #pragma unroll
        for (int kc = 0; kc < 2; ++kc)
            #pragma unroll
            for (int mt = 0; mt < 4; ++mt)
                acc[4 + mt] = __builtin_amdgcn_mfma_f32_16x16x32_bf16(
                    afh[kc][mt], bfr[kc], acc[4 + mt], 0, 0, 0);
        __builtin_amdgcn_s_setprio(0);

        // boundary: force tile t+1 complete, keep t+2's 5 loads in flight
        if (t < 14)       asm volatile("s_waitcnt vmcnt(5)\ns_barrier" ::: "memory");
        else if (t == 14) asm volatile("s_waitcnt vmcnt(0)\ns_barrier" ::: "memory");
        // t == 15: no further LDS use; fall through to epilogue
    }
#undef BT_STAGE

    const int col = bn + wn4 * 16 + l15;
    const float bv = bias[col];
    #pragma unroll
    for (int mt = 0; mt < 8; ++mt) {
        const int row = bm + wm2 * 128 + mt * 16 + lq * 4;
        #pragma unroll
        for (int r = 0; r < 4; ++r)
            Cm[(size_t)(row + r) * N + col] = acc[mt][r] + bv;
    }
}

// ---------------------------------------------------------------------------
extern "C" void kernel_launch(void* const* d_in, const int* in_sizes, int n_in,
                              void* d_out, int out_size, void* d_ws, size_t ws_size,
                              hipStream_t stream)
{
    const float* x      = (const float*)d_in[0];
    const float* w_qkv  = (const float*)d_in[1];
    const float* w_proj = (const float*)d_in[2];
    const float* b_proj = (const float*)d_in[3];
    float*       out    = (float*)d_out;

    // workspace: 48 MiB
    unsigned short* xb     = (unsigned short*)d_ws;                 // [4096][1024]
    unsigned short* wqkvT  = xb     + (size_t)M_ROWS * C_DIM;       // [3072][1024]
    unsigned short* wprojT = wqkvT  + (size_t)QKV_N * C_DIM;        // [1024][1024]
    unsigned short* qbuf   = wprojT + (size_t)C_DIM * C_DIM;        // [32][2048][64]
    unsigned short* kbuf   = qbuf   + (size_t)M_ROWS * C_DIM;       // [32][2048][64]
    unsigned short* vbuf   = kbuf   + (size_t)M_ROWS * C_DIM;       // [32][64][2048]
    unsigned short* attnb  = vbuf   + (size_t)M_ROWS * C_DIM;       // [4096][1024]

    // 0) fused prep (x convert + both weight transposes)
    prep_fused<<<4096 + 768 + 256, 256, 0, stream>>>(x, xb, w_qkv, wqkvT, w_proj, wprojT);

    // 1) QKV projection (256x192 tile, counted-vmcnt pipeline + deferred
    //    cluster-2, 112 KB dyn LDS, 256 blocks = 1/CU, transpose epilogue)
    gemm_qkv<<<256, 512, 114688, stream>>>(xb, wqkvT, qbuf, kbuf, vbuf);

    // 2) flash attention (R8: 8 waves, 2 key-groups x 32 q-rows/wave,
    //    512 blocks, super-tile double-buffer)
    attn_mfma<<<512, 512, 0, stream>>>(qbuf, kbuf, vbuf, attnb);

    // 3) output projection + bias (256x64 tile, counted-vmcnt pipeline,
    //    96 KB dyn LDS request -> 1 block/CU, 256 blocks)
    gemm_bt<<<256, 512, 98304, stream>>>(attnb, wprojT, b_proj, out, M_ROWS, C_DIM, C_DIM);
}

// Round 14
// 173.501 us; speedup vs baseline: 1.0148x; 1.0148x over previous
//
#include <hip/hip_runtime.h>
#include <hip/hip_bf16.h>
#include <math.h>

// Problem constants (match reference setup_inputs)
#define B_SZ   2
#define N_SEQ  2048
#define C_DIM  1024
#define H_NUM  16
#define D_HEAD 64
#define M_ROWS (B_SZ * N_SEQ)   // 4096
#define QKV_N  (3 * C_DIM)      // 3072

typedef __attribute__((ext_vector_type(8))) short  bf16x8;
typedef __attribute__((ext_vector_type(4))) float  floatx4;

// fp32 -> bf16 bits, round-to-nearest-even
static __device__ __forceinline__ unsigned short f2bf(float x) {
    unsigned int u = __float_as_uint(x);
    u = (u + 0x7FFFu + ((u >> 16) & 1u)) >> 16;
    return (unsigned short)u;
}
// RNE-rounded bits kept in the high halfword (for pair packing via v_perm)
static __device__ __forceinline__ unsigned int f2bf_hi(float x) {
    unsigned int u = __float_as_uint(x);
    return u + 0x7FFFu + ((u >> 16) & 1u);
}
// pack (lo=a, hi=b) as two RNE bf16 in one u32
#if __has_builtin(__builtin_amdgcn_cvt_pk_bf16_f32)
typedef __bf16 bf16_2 __attribute__((ext_vector_type(2)));
static __device__ __forceinline__ unsigned int pkbf(float a, float b) {
    union { bf16_2 v; unsigned int u; } c;
    c.v = __builtin_amdgcn_cvt_pk_bf16_f32(a, b);
    return c.u;
}
#else
static __device__ __forceinline__ unsigned int pkbf(float a, float b) {
    return __builtin_amdgcn_perm(f2bf_hi(b), f2bf_hi(a), 0x07060302u);
}
#endif

#if __has_builtin(__builtin_amdgcn_exp2f)
#define EXP2F(x) __builtin_amdgcn_exp2f(x)
#else
#define EXP2F(x) exp2f(x)
#endif

#define GLP(p) ((const __attribute__((address_space(1))) void*)(p))
#define LDP(p) ((__attribute__((address_space(3))) void*)(p))

#define CEXP 0.18033688011112042f   // 0.125 * log2(e)

// ---------------------------------------------------------------------------
// Fused prep (1 launch): blocks [0,4096) convert x to bf16;
// [4096,4864) transpose-convert w_qkv; [4864,5120) transpose-convert w_proj.
// ---------------------------------------------------------------------------
__global__ __launch_bounds__(256)
void prep_fused(const float* __restrict__ x,      unsigned short* __restrict__ xb,
                const float* __restrict__ w_qkv,  unsigned short* __restrict__ wqkvT,
                const float* __restrict__ w_proj, unsigned short* __restrict__ wprojT)
{
    __shared__ unsigned short t[64][72];
    const int bid = blockIdx.x;
    const int tid = threadIdx.x;

    if (bid < 4096) {                        // x -> bf16 (exactly 1M float4 groups)
        const int i = bid * 256 + tid;
        float4 v = ((const float4*)x)[i];
        ushort4 p;
        p.x = f2bf(v.x); p.y = f2bf(v.y); p.z = f2bf(v.z); p.w = f2bf(v.w);
        ((ushort4*)xb)[i] = p;
        return;
    }

    const float* W;
    unsigned short* WT;
    int N, tt;
    if (bid < 4096 + 768) { W = w_qkv;  WT = wqkvT;  N = QKV_N; tt = bid - 4096; }
    else                  { W = w_proj; WT = wprojT; N = C_DIM; tt = bid - 4864; }
    const int ntiles = N / 64;
    const int n0 = (tt % ntiles) * 64;
    const int k0 = (tt / ntiles) * 64;
    const int K  = C_DIM;

    const int tc = tid & 15;
    const int tr = tid >> 4;
    #pragma unroll
    for (int p = 0; p < 4; ++p) {
        const int r = tr + p * 16;
        float4 v = *(const float4*)&W[(size_t)(k0 + r) * N + n0 + tc * 4];
        ushort4 pk;
        pk.x = f2bf(v.x); pk.y = f2bf(v.y); pk.z = f2bf(v.z); pk.w = f2bf(v.w);
        *(ushort4*)&t[r][tc * 4] = pk;
    }
    __syncthreads();

    const int n  = tid >> 2;
    const int c0 = (tid & 3) * 16;
    unsigned short tmp[16];
    #pragma unroll
    for (int i = 0; i < 16; ++i) tmp[i] = t[c0 + i][n];
    *(uint4*)&WT[(size_t)(n0 + n) * K + k0 + c0]     = *(uint4*)&tmp[0];
    *(uint4*)&WT[(size_t)(n0 + n) * K + k0 + c0 + 8] = *(uint4*)&tmp[8];
}

// ---------------------------------------------------------------------------
// QKV GEMM -- R18 (measured best 175.9 us): 256(M) x 192(N) tile,
// counted-vmcnt deep pipeline, grid 16x16 = 256 blocks = exactly 1/CU,
// LDS-transpose epilogue. Schedule per K-tile:
//   read A-low+B frags -> 24 MFMA -> read A-high frags
//   -> [lgkmcnt(0); s_barrier]   (buf free: all reads in regs)
//   -> issue 7 global_load_lds for tile t+2 into freed buffer
//   -> 24 MFMA
//   -> [vmcnt(7); s_barrier]     (tile t+1 complete; t+2's 7 in flight)
// R19's deferred cluster-2 was NULL (within noise) -> reverted; the 2nd
// wave/SIMD already covers the barrier-wake window at this occupancy.
// 512 thr = 8 waves (2M x 4N), per-wave 128x48 output (acc[8][3]).
// LDS 112 KB dyn: A[2][256x64] + B[2][192x64]. Bijective XCD swizzle.
// Epilogue: WRITE_SIZE was 1.9x actual output with direct scalar stores
// (L2 RMW amplification); fixed via LDS col-major transpose + 16B coalesced
// stores. q pre-scaled by CEXP; v keys permuted per-64 via inverse-fk runs.
// ---------------------------------------------------------------------------
__global__ __launch_bounds__(512, 2)
void gemm_qkv(const unsigned short* __restrict__ A,   // xb [4096][1024]
              const unsigned short* __restrict__ BT,  // wqkvT [3072][1024]
              unsigned short* __restrict__ qbuf,
              unsigned short* __restrict__ kbuf,
              unsigned short* __restrict__ vbuf)
{
    extern __shared__ unsigned short lds2[];     // 112 KB
    unsigned short* AsB = lds2;                  // [2][256*64] = 32768 ushorts
    unsigned short* BsB = lds2 + 32768;          // [2][192*64] = 24576 ushorts

    const int K = C_DIM;
    const int tid  = threadIdx.x;
    const int lane = tid & 63;
    const int wave = tid >> 6;        // 0..7
    const int wm2  = wave >> 2;       // 0..1  M-half (128 rows)
    const int wn4  = wave & 3;        // 0..3  N-quarter (48 cols)
    const int l15  = lane & 15;
    const int lq   = lane >> 4;
    const int e7   = l15 & 7;

    // grid 256 = 16(M) x 16(N); bijective XCD swizzle (32 blocks per XCD)
    const int bid = blockIdx.x;                  // 0..255
    const int g   = (bid & 7) * 32 + (bid >> 3); // 0..255
    const int bm  = (g & 15) * 256;
    const int bn  = (g >> 4) * 192;

    // staging: 7 issues per K-tile (4 A + 3 B), each 512 thr x 16B = 8 KB.
    // issue i covers rows i*64 + srow; swizzle issue-invariant (64 % 8 == 0).
    const int srow = tid >> 3;                       // 0..63
    const int gso  = ((tid & 7) ^ (srow & 7)) * 8;   // logical col chunk

    const unsigned short* ga = A  + (size_t)(bm + srow) * K + gso;
    const unsigned short* gb = BT + (size_t)(bn + srow) * K + gso;

    floatx4 acc[8][3];
    #pragma unroll
    for (int i = 0; i < 8; ++i)
        #pragma unroll
        for (int j = 0; j < 3; ++j) acc[i][j] = (floatx4){0.f, 0.f, 0.f, 0.f};

#define QKV_STAGE(t_, buf_)                                                    \
    {                                                                          \
        unsigned short* Ad_ = AsB + (buf_) * 16384;                            \
        unsigned short* Bd_ = BsB + (buf_) * 12288;                            \
        _Pragma("unroll")                                                      \
        for (int i_ = 0; i_ < 4; ++i_)                                         \
            __builtin_amdgcn_global_load_lds(                                  \
                GLP(ga + (size_t)i_ * 64 * K + (t_) * 64),                     \
                LDP(Ad_ + i_ * 4096 + tid * 8), 16, 0, 0);                     \
        _Pragma("unroll")                                                      \
        for (int i_ = 0; i_ < 3; ++i_)                                         \
            __builtin_amdgcn_global_load_lds(                                  \
                GLP(gb + (size_t)i_ * 64 * K + (t_) * 64),                     \
                LDP(Bd_ + i_ * 4096 + tid * 8), 16, 0, 0);                     \
    }

    // prologue: stage tiles 0 and 1; wait tile 0 (7 of 14 loads) only.
    QKV_STAGE(0, 0);
    QKV_STAGE(1, 1);
    asm volatile("s_waitcnt vmcnt(7)\ns_barrier" ::: "memory");

    for (int t = 0; t < 16; ++t) {
        const int cur = t & 1;
        const unsigned short* Ac = AsB + cur * 16384;
        const unsigned short* Bc = BsB + cur * 12288;

        // frag reads: A-low half (m-frags 0..3) + all B
        bf16x8 afl[2][4], bfr[2][3];
        #pragma unroll
        for (int kc = 0; kc < 2; ++kc) {
            #pragma unroll
            for (int mt = 0; mt < 4; ++mt)
                afl[kc][mt] = *(const bf16x8*)&Ac[(wm2 * 128 + mt * 16 + l15) * 64
                                                  + (((kc * 4 + lq) ^ e7) * 8)];
            #pragma unroll
            for (int nt = 0; nt < 3; ++nt)
                bfr[kc][nt] = *(const bf16x8*)&Bc[(wn4 * 48 + nt * 16 + l15) * 64
                                                  + (((kc * 4 + lq) ^ e7) * 8)];
        }

        // MFMA cluster 1 (m-frags 0..3)
        __builtin_amdgcn_s_setprio(1);
        #pragma unroll
        for (int kc = 0; kc < 2; ++kc)
            #pragma unroll
            for (int mt = 0; mt < 4; ++mt)
                #pragma unroll
                for (int nt = 0; nt < 3; ++nt)
                    acc[mt][nt] = __builtin_amdgcn_mfma_f32_16x16x32_bf16(
                        afl[kc][mt], bfr[kc][nt], acc[mt][nt], 0, 0, 0);
        __builtin_amdgcn_s_setprio(0);

        // frag reads: A-high half (m-frags 4..7)
        bf16x8 afh[2][4];
        #pragma unroll
        for (int kc = 0; kc < 2; ++kc)
            #pragma unroll
            for (int mt = 0; mt < 4; ++mt)
                afh[kc][mt] = *(const bf16x8*)&Ac[(wm2 * 128 + 64 + mt * 16 + l15) * 64
                                                  + (((kc * 4 + lq) ^ e7) * 8)];

        // all reads of buf[cur] are in regs after this -> buffer free
        asm volatile("s_waitcnt lgkmcnt(0)\ns_barrier" ::: "memory");

        // prefetch tile t+2 into the just-freed buffer (same parity)
        if (t < 14) QKV_STAGE(t + 2, cur);

        // MFMA cluster 2 (m-frags 4..7)
        __builtin_amdgcn_s_setprio(1);
        #pragma unroll
        for (int kc = 0; kc < 2; ++kc)
            #pragma unroll
            for (int mt = 0; mt < 4; ++mt)
                #pragma unroll
                for (int nt = 0; nt < 3; ++nt)
                    acc[4 + mt][nt] = __builtin_amdgcn_mfma_f32_16x16x32_bf16(
                        afh[kc][mt], bfr[kc][nt], acc[4 + mt][nt], 0, 0, 0);
        __builtin_amdgcn_s_setprio(0);

        // boundary: force tile t+1 complete, keep t+2's 7 loads in flight
        if (t < 14)       asm volatile("s_waitcnt vmcnt(7)\ns_barrier" ::: "memory");
        else if (t == 14) asm volatile("s_waitcnt vmcnt(0)\ns_barrier" ::: "memory");
        // t == 15: no further LDS use until the epilogue barrier below
    }
#undef QKV_STAGE

    // ---- R18 epilogue: LDS col-major transpose, then coalesced stores ----
    // Tc[192][256] bf16 col-major image, 96 KB (fits the 112 KB allocation).
    // Element index: cc*256 + (r ^ xr(cc)), xr(cc) = ((2cc + (cc>>3)) & 31) << 2.
    asm volatile("s_waitcnt lgkmcnt(0)\ns_barrier" ::: "memory");
    unsigned short* Tc = lds2;

    // write phase: each lane writes 24 x 8B (4 consecutive rows, one col)
    #pragma unroll
    for (int nt = 0; nt < 3; ++nt) {
        const int lc   = wn4 * 48 + nt * 16 + l15;     // local col 0..191
        const int gcol = bn + lc;                      // global col
        const float sc = ((gcol >> 10) == 0) ? CEXP : 1.0f;  // q pre-scale
        const int xr   = ((2 * lc + (lc >> 3)) & 31) << 2;
        #pragma unroll
        for (int mt = 0; mt < 8; ++mt) {
            const int r0 = wm2 * 128 + mt * 16 + lq * 4;     // aligned 4
            unsigned int* p = (unsigned int*)&Tc[lc * 256 + (r0 ^ xr)];
            p[0] = pkbf(acc[mt][nt][0] * sc, acc[mt][nt][1] * sc);
            p[1] = pkbf(acc[mt][nt][2] * sc, acc[mt][nt][3] * sc);
        }
    }
    asm volatile("s_waitcnt lgkmcnt(0)\ns_barrier" ::: "memory");

    // read + coalesced-store phase, per 64-col head chunk
    const int bq = bm >> 11;           // batch (uniform per block)
    const int nb = bm & 2047;          // row base within batch
    #pragma unroll
    for (int hc = 0; hc < 3; ++hc) {
        const int colg = bn + hc * 64;
        const int reg3 = colg >> 10;               // 0=q, 1=k, 2=v
        const int h    = (colg >> 6) & 15;
        if (reg3 < 2) {
            // dest: contiguous 256x64 bf16 block, row-major [n][d]
            unsigned short* dstb = (reg3 ? kbuf : qbuf)
                + ((size_t)(bq * H_NUM + h) * N_SEQ + nb) * D_HEAD;
            const int col0 = (tid & 7) * 8;        // 0..56
            const int row  = tid >> 3;             // 0..63
            #pragma unroll
            for (int rr = 0; rr < 4; ++rr) {
                const int r = row + rr * 64;       // 0..255
                union { unsigned short s[8]; uint4 v; } u;
                #pragma unroll
                for (int c = 0; c < 8; ++c) {
                    const int cc = hc * 64 + col0 + c;
                    const int xr = ((2 * cc + (cc >> 3)) & 31) << 2;
                    u.s[c] = Tc[cc * 256 + (r ^ xr)];
                }
                *(uint4*)&dstb[(size_t)r * D_HEAD + col0] = u.v;
            }
        } else {
            // dest: vbuf[(bq*16+h)*64 + d][ (n&~63) + fk(n&63) ]
            // inverse perm: source a(p) = (p&0x23)|((p&0x18)>>1)|((p&4)<<2);
            // 16B dest run p0..p0+7 -> two 8B source runs {ab..+3},{ab+16..+19}
            unsigned short* dstb = vbuf
                + (size_t)(bq * H_NUM + h) * D_HEAD * N_SEQ;
            const int d  = tid >> 3;               // 0..63
            const int p0 = (tid & 7) * 8;          // 0..56
            const int cc = hc * 64 + d;
            const int ab = (p0 & 0x23) | ((p0 & 0x18) >> 1) | ((p0 & 4) << 2);
            const int xr = ((2 * cc + (cc >> 3)) & 31) << 2;
            #pragma unroll
            for (int gg = 0; gg < 4; ++gg) {
                const int rb = gg * 64;
                ushort4 ra = *(ushort4*)&Tc[cc * 256 + ((rb + ab) ^ xr)];
                ushort4 rc = *(ushort4*)&Tc[cc * 256 + ((rb + ab + 16) ^ xr)];
                union { unsigned short s[8]; uint4 v; } u;
                u.s[0] = ra.x; u.s[1] = ra.y; u.s[2] = ra.z; u.s[3] = ra.w;
                u.s[4] = rc.x; u.s[5] = rc.y; u.s[6] = rc.z; u.s[7] = rc.w;
                *(uint4*)&dstb[(size_t)d * N_SEQ + nb + rb + p0] = u.v;
            }
        }
    }
}

// ---------------------------------------------------------------------------
// S^T-form bf16 MFMA flash attention, fixed-max softmax. R8 EXACT (measured
// best: 51.0 us): 8 waves/block (512 thr), waves split into 2 KEY-groups --
// grp0 (waves 0-3) even 64-key tiles, grp1 (waves 4-7) odd tiles, lockstep
// 128-key super-tiles. Fixed-max softmax => partial (O,l) over disjoint key
// sets add exactly; one LDS combine at the end.
// Grid = 512 blocks (2 blocks/CU, 16 waves/CU = 4 waves/SIMD).
// LDS: 4 K-tiles + 4 V-tiles = 64 KB, double-buffered at super-tile level.
// Register audit (why occupancy can't go higher): acc 32 + qf 16 + pf 16 +
// addressing ~= 112 unified regs/wave -> 4 waves/SIMD is the cap; fewer
// q-rows/wave halves state but doubles per-CU LDS traffic (R6 regression).
// q pre-scaled by CEXP; S-acc init -8 folds the softmax shift.
// ---------------------------------------------------------------------------
__global__ __launch_bounds__(512, 4)
void attn_mfma(const unsigned short* __restrict__ qbuf,
               const unsigned short* __restrict__ kbuf,
               const unsigned short* __restrict__ vbuf,
               unsigned short* __restrict__ attnb)
{
    __shared__ unsigned short KsS[2][2][64 * 64];   // [pair][tile-in-pair] 32 KB
    __shared__ unsigned short VtS[2][2][64 * 64];   // 32 KB

    const int tid  = threadIdx.x;
    const int lane = tid & 63;
    const int wave = tid >> 6;           // 0..7
    const int grp  = wave >> 2;          // 0: even tiles, 1: odd tiles
    const int wrow = wave & 3;           // q-row group within block
    const int l15  = lane & 15;
    const int lq   = lane >> 4;
    const int e    = l15 & 7;

    // XCD swizzle: low 3 bits pick XCD; same bh stays in one XCD group
    const int bid  = blockIdx.x;                    // 0..511
    const int bh   = (bid & 7) * 4 + (bid >> 7);    // 0..31
    const int qblk = (bid >> 3) & 15;               // 0..15
    const int b    = bh >> 4;
    const int h    = bh & 15;
    const int q0   = qblk * 128 + wrow * 32;

    const unsigned short* khead = kbuf + (size_t)bh * N_SEQ * D_HEAD;
    const unsigned short* vhead = vbuf + (size_t)bh * D_HEAD * N_SEQ;

    // Q B-frags, 2 q-column blocks (q pre-scaled by CEXP at gemm_qkv)
    bf16x8 qf[2][2];   // [kchunk][qb]
    #pragma unroll
    for (int qb = 0; qb < 2; ++qb) {
        const unsigned short* qrow = qbuf
            + ((size_t)bh * N_SEQ + q0 + qb * 16 + l15) * D_HEAD + lq * 8;
        qf[0][qb] = *(const bf16x8*)qrow;
        qf[1][qb] = *(const bf16x8*)(qrow + 32);
    }

    floatx4 acc[4][2];
    #pragma unroll
    for (int dc = 0; dc < 4; ++dc)
        #pragma unroll
        for (int qb = 0; qb < 2; ++qb) acc[dc][qb] = (floatx4){0.f, 0.f, 0.f, 0.f};
    float lsum[2] = {0.f, 0.f};

    // staging: 512 threads x 16B = one full 8KB tile per issue.
    // row = tid>>3 (0..63), phys seg = tid&7, global col chunk = seg^(row&7)
    const int srow = tid >> 3;                        // 0..63
    const int gso  = ((tid & 7) ^ (srow & 7)) * 8;

    // prologue: stage super-tile 0 (key tiles 0,1) into pair 0
    #pragma unroll
    for (int i = 0; i < 2; ++i) {
        __builtin_amdgcn_global_load_lds(GLP(khead + (size_t)(i * 64 + srow) * 64 + gso),
                                         LDP(&KsS[0][i][tid * 8]), 16, 0, 0);
        __builtin_amdgcn_global_load_lds(GLP(vhead + (size_t)srow * N_SEQ + i * 64 + gso),
                                         LDP(&VtS[0][i][tid * 8]), 16, 0, 0);
    }

    for (int s = 0; s < N_SEQ / 128; ++s) {
        const int cur = s & 1;
        __syncthreads();   // drains DMA for pair cur; prior reads of cur^1 done

        if (s + 1 < N_SEQ / 128) {
            const int m1 = (s + 1) * 128;
            const int nx = cur ^ 1;
            #pragma unroll
            for (int i = 0; i < 2; ++i) {
                __builtin_amdgcn_global_load_lds(
                    GLP(khead + (size_t)(m1 + i * 64 + srow) * 64 + gso),
                    LDP(&KsS[nx][i][tid * 8]), 16, 0, 0);
                __builtin_amdgcn_global_load_lds(
                    GLP(vhead + (size_t)srow * N_SEQ + m1 + i * 64 + gso),
                    LDP(&VtS[nx][i][tid * 8]), 16, 0, 0);
            }
        }

        const unsigned short* Ksc = &KsS[cur][grp][0];
        const unsigned short* Vtc = &VtS[cur][grp][0];

        // S^T = K Q^T (acc init -8 folds the softmax shift); K frags shared
        // across both q-blocks.
        floatx4 st[4][2];
        #pragma unroll
        for (int t = 0; t < 4; ++t) {
            bf16x8 k0 = *(const bf16x8*)&Ksc[(t * 16 + l15) * 64 + ((lq ^ e) * 8)];
            bf16x8 k1 = *(const bf16x8*)&Ksc[(t * 16 + l15) * 64 + (((4 + lq) ^ e) * 8)];
            #pragma unroll
            for (int qb = 0; qb < 2; ++qb) {
                floatx4 sv = (floatx4){-8.f, -8.f, -8.f, -8.f};
                sv = __builtin_amdgcn_mfma_f32_16x16x32_bf16(k0, qf[0][qb], sv, 0, 0, 0);
                sv = __builtin_amdgcn_mfma_f32_16x16x32_bf16(k1, qf[1][qb], sv, 0, 0, 0);
                st[t][qb] = sv;
            }
        }

        // fixed-max softmax: p = 2^st; packed RNE bf16 pairs
        bf16x8 pf[2][2];   // [kchunk][qb]
        #pragma unroll
        for (int qb = 0; qb < 2; ++qb) {
            unsigned int pk[8];
            float la = 0.f;
            #pragma unroll
            for (int t = 0; t < 4; ++t) {
                float p0 = EXP2F(st[t][qb][0]);
                float p1 = EXP2F(st[t][qb][1]);
                float p2 = EXP2F(st[t][qb][2]);
                float p3 = EXP2F(st[t][qb][3]);
                la += (p0 + p1) + (p2 + p3);
                pk[t * 2]     = pkbf(p0, p1);
                pk[t * 2 + 1] = pkbf(p2, p3);
            }
            lsum[qb] += la;
            union { uint4 u; bf16x8 v; } c0, c1;
            c0.u = make_uint4(pk[0], pk[1], pk[2], pk[3]);
            c1.u = make_uint4(pk[4], pk[5], pk[6], pk[7]);
            pf[0][qb] = c0.v;
            pf[1][qb] = c1.v;
        }

        // O^T += V^T P^T; V frags shared across both q-blocks
        #pragma unroll
        for (int dc = 0; dc < 4; ++dc) {
            bf16x8 v0 = *(const bf16x8*)&Vtc[(dc * 16 + l15) * 64 + ((lq ^ e) * 8)];
            bf16x8 v1 = *(const bf16x8*)&Vtc[(dc * 16 + l15) * 64 + (((4 + lq) ^ e) * 8)];
            #pragma unroll
            for (int qb = 0; qb < 2; ++qb) {
                acc[dc][qb] = __builtin_amdgcn_mfma_f32_16x16x32_bf16(
                    v0, pf[0][qb], acc[dc][qb], 0, 0, 0);
                acc[dc][qb] = __builtin_amdgcn_mfma_f32_16x16x32_bf16(
                    v1, pf[1][qb], acc[dc][qb], 0, 0, 0);
            }
        }
    }

    // cross-group combine (disjoint key sets => partials add exactly).
    // grp1 writes acc (32 f32/lane, XOR-swizzled: conflict-free) + lsum to
    // LDS; grp0 adds, normalizes, stores.
    __syncthreads();
    float* smA = (float*)&KsS[0][0][0];   // 32 KB: 4 waves x 64 lanes x 32 f32
    float* smL = (float*)&VtS[0][0][0];   // lsum partials
    const int li = wrow * 64 + lane;
    if (grp) {
        float* p = smA + li * 32;
        #pragma unroll
        for (int dc = 0; dc < 4; ++dc)
            #pragma unroll
            for (int qb = 0; qb < 2; ++qb)
                #pragma unroll
                for (int r = 0; r < 4; ++r)
                    p[(dc * 8 + qb * 4 + r) ^ (lane & 31)] = acc[dc][qb][r];
        smL[li * 2]     = lsum[0];
        smL[li * 2 + 1] = lsum[1];
    }
    __syncthreads();
    if (grp) return;

    {
        const float* p = smA + li * 32;
        #pragma unroll
        for (int dc = 0; dc < 4; ++dc)
            #pragma unroll
            for (int qb = 0; qb < 2; ++qb)
                #pragma unroll
                for (int r = 0; r < 4; ++r)
                    acc[dc][qb][r] += p[(dc * 8 + qb * 4 + r) ^ (lane & 31)];
        lsum[0] += smL[li * 2];
        lsum[1] += smL[li * 2 + 1];
    }

    // epilogue: reduce l across lq groups, normalize, store bf16
    #pragma unroll
    for (int qb = 0; qb < 2; ++qb) {
        float l = lsum[qb];
        l += __shfl_xor(l, 16, 64);
        l += __shfl_xor(l, 32, 64);
        const float inv = 1.f / l;
        const int q = q0 + qb * 16 + l15;
        unsigned short* orow = attnb + ((size_t)b * N_SEQ + q) * C_DIM + h * D_HEAD;
        #pragma unroll
        for (int dc = 0; dc < 4; ++dc) {
            ushort4 pkk;
            pkk.x = f2bf(acc[dc][qb][0] * inv);
            pkk.y = f2bf(acc[dc][qb][1] * inv);
            pkk.z = f2bf(acc[dc][qb][2] * inv);
            pkk.w = f2bf(acc[dc][qb][3] * inv);
            *(ushort4*)&orow[dc * 16 + lq * 4] = pkk;
        }
    }
}

// ---------------------------------------------------------------------------
// Output projection GEMM -- R17: counted-vmcnt pipeline port (same template
// as gemm_qkv R16). 256(M) x 64(N) tile, grid 16x16 = 256 blocks = 1/CU.
// 512 thr = 8 waves (2M x 4N), per-wave 128x16 output (acc[8], 32 regs).
// Staging 5 loads/K-tile (4 A + 1 B; B-tile 64x64 = one full 8KB issue);
// boundary vmcnt(5). LDS 80 KB (A 2x32 + B 2x8), padded to 96 KB request to
// pin exactly 1 block/CU. fp32 out + bias.
// ---------------------------------------------------------------------------
__global__ __launch_bounds__(512, 2)
void gemm_bt(const unsigned short* __restrict__ A,   // [M][K] bf16
             const unsigned short* __restrict__ BT,  // [N][K] bf16
             const float* __restrict__ bias,         // [N] fp32
             float* __restrict__ Cm,
             int M, int N, int K)
{
    extern __shared__ unsigned short ldsb[];     // 96 KB requested
    unsigned short* AsB = ldsb;                  // [2][256*64] = 32768 ushorts
    unsigned short* BsB = ldsb + 32768;          // [2][64*64]  = 8192 ushorts

    const int tid  = threadIdx.x;
    const int lane = tid & 63;
    const int wave = tid >> 6;        // 0..7
    const int wm2  = wave >> 2;       // 0..1  M-half (128 rows)
    const int wn4  = wave & 3;        // 0..3  N-quarter (16 cols)
    const int l15  = lane & 15;
    const int lq   = lane >> 4;
    const int e7   = l15 & 7;

    // grid 256 = 16(M) x 16(N); bijective XCD swizzle (32 blocks per XCD)
    const int bid = blockIdx.x;                  // 0..255
    const int g   = (bid & 7) * 32 + (bid >> 3); // 0..255
    const int bm  = (g & 15) * 256;
    const int bn  = (g >> 4) * 64;

    const int srow = tid >> 3;                       // 0..63
    const int gso  = ((tid & 7) ^ (srow & 7)) * 8;   // logical col chunk

    const unsigned short* ga = A  + (size_t)(bm + srow) * K + gso;
    const unsigned short* gb = BT + (size_t)(bn + srow) * K + gso;

    floatx4 acc[8];
    #pragma unroll
    for (int i = 0; i < 8; ++i) acc[i] = (floatx4){0.f, 0.f, 0.f, 0.f};

#define BT_STAGE(t_, buf_)                                                     \
    {                                                                          \
        unsigned short* Ad_ = AsB + (buf_) * 16384;                            \
        unsigned short* Bd_ = BsB + (buf_) * 4096;                             \
        _Pragma("unroll")                                                      \
        for (int i_ = 0; i_ < 4; ++i_)                                         \
            __builtin_amdgcn_global_load_lds(                                  \
                GLP(ga + (size_t)i_ * 64 * K + (t_) * 64),                     \
                LDP(Ad_ + i_ * 4096 + tid * 8), 16, 0, 0);                     \
        __builtin_amdgcn_global_load_lds(                                      \
            GLP(gb + (t_) * 64),                                               \
            LDP(Bd_ + tid * 8), 16, 0, 0);                                     \
    }

    // prologue: stage tiles 0 and 1; wait tile 0 (5 of 10 loads) only.
    BT_STAGE(0, 0);
    BT_STAGE(1, 1);
    asm volatile("s_waitcnt vmcnt(5)\ns_barrier" ::: "memory");

    for (int t = 0; t < 16; ++t) {
        const int cur = t & 1;
        const unsigned short* Ac = AsB + cur * 16384;
        const unsigned short* Bc = BsB + cur * 4096;

        // frag reads: A-low half (m-frags 0..3) + B
        bf16x8 afl[2][4], bfr[2];
        #pragma unroll
        for (int kc = 0; kc < 2; ++kc) {
            #pragma unroll
            for (int mt = 0; mt < 4; ++mt)
                afl[kc][mt] = *(const bf16x8*)&Ac[(wm2 * 128 + mt * 16 + l15) * 64
                                                  + (((kc * 4 + lq) ^ e7) * 8)];
            bfr[kc] = *(const bf16x8*)&Bc[(wn4 * 16 + l15) * 64
                                          + (((kc * 4 + lq) ^ e7) * 8)];
        }

        // MFMA cluster 1 (m-frags 0..3)
        __builtin_amdgcn_s_setprio(1);
        #pragma unroll
        for (int kc = 0; kc < 2; ++kc)
            #pragma unroll
            for (int mt = 0; mt < 4; ++mt)
                acc[mt] = __builtin_amdgcn_mfma_f32_16x16x32_bf16(
                    afl[kc][mt], bfr[kc], acc[mt], 0, 0, 0);
        __builtin_amdgcn_s_setprio(0);

        // frag reads: A-high half (m-frags 4..7)
        bf16x8 afh[2][4];
        #pragma unroll
        for (int kc = 0; kc < 2; ++kc)
            #pragma unroll
            for (int mt = 0; mt < 4; ++mt)
                afh[kc][mt] = *(const bf16x8*)&Ac[(wm2 * 128 + 64 + mt * 16 + l15) * 64
                                                  + (((kc * 4 + lq) ^ e7) * 8)];

        // all reads of buf[cur] are in regs after this -> buffer free
        asm volatile("s_waitcnt lgkmcnt(0)\ns_barrier" ::: "memory");

        // prefetch tile t+2 into the just-freed buffer (same parity)
        if (t < 14) BT_STAGE(t + 2, cur);

        // MFMA cluster 2 (m-frags 4..7)
        __builtin_amdgcn_s_setprio(1);
        #pragma unroll
        for (int kc = 0; kc < 2; ++kc)
            #pragma unroll
            for (int mt = 0; mt < 4; ++mt)
                acc[4 + mt] = __builtin_amdgcn_mfma_f32_16x16x32_bf16(
                    afh[kc][mt], bfr[kc], acc[4 + mt], 0, 0, 0);
        __builtin_amdgcn_s_setprio(0);

        // boundary: force tile t+1 complete, keep t+2's 5 loads in flight
        if (t < 14)       asm volatile("s_waitcnt vmcnt(5)\ns_barrier" ::: "memory");
        else if (t == 14) asm volatile("s_waitcnt vmcnt(0)\ns_barrier" ::: "memory");
        // t == 15: no further LDS use; fall through to epilogue
    }
#undef BT_STAGE

    const int col = bn + wn4 * 16 + l15;
    const float bv = bias[col];
    #pragma unroll
    for (int mt = 0; mt < 8; ++mt) {
        const int row = bm + wm2 * 128 + mt * 16 + lq * 4;
        #pragma unroll
        for (int r = 0; r < 4; ++r)
            Cm[(size_t)(row + r) * N + col] = acc[mt][r] + bv;
    }
}

// ---------------------------------------------------------------------------
extern "C" void kernel_launch(void* const* d_in, const int* in_sizes, int n_in,
                              void* d_out, int out_size, void* d_ws, size_t ws_size,
                              hipStream_t stream)
{
    const float* x      = (const float*)d_in[0];
    const float* w_qkv  = (const float*)d_in[1];
    const float* w_proj = (const float*)d_in[2];
    const float* b_proj = (const float*)d_in[3];
    float*       out    = (float*)d_out;

    // workspace: 48 MiB
    unsigned short* xb     = (unsigned short*)d_ws;                 // [4096][1024]
    unsigned short* wqkvT  = xb     + (size_t)M_ROWS * C_DIM;       // [3072][1024]
    unsigned short* wprojT = wqkvT  + (size_t)QKV_N * C_DIM;        // [1024][1024]
    unsigned short* qbuf   = wprojT + (size_t)C_DIM * C_DIM;        // [32][2048][64]
    unsigned short* kbuf   = qbuf   + (size_t)M_ROWS * C_DIM;       // [32][2048][64]
    unsigned short* vbuf   = kbuf   + (size_t)M_ROWS * C_DIM;       // [32][64][2048]
    unsigned short* attnb  = vbuf   + (size_t)M_ROWS * C_DIM;       // [4096][1024]

    // 0) fused prep (x convert + both weight transposes)
    prep_fused<<<4096 + 768 + 256, 256, 0, stream>>>(x, xb, w_qkv, wqkvT, w_proj, wprojT);

    // 1) QKV projection (256x192 tile, counted-vmcnt pipeline, 112 KB dyn LDS,
    //    256 blocks = exactly 1/CU, LDS-transpose epilogue)
    gemm_qkv<<<256, 512, 114688, stream>>>(xb, wqkvT, qbuf, kbuf, vbuf);

    // 2) flash attention (R8: 8 waves, 2 key-groups x 32 q-rows/wave,
    //    512 blocks, super-tile double-buffer)
    attn_mfma<<<512, 512, 0, stream>>>(qbuf, kbuf, vbuf, attnb);

    // 3) output projection + bias (256x64 tile, counted-vmcnt pipeline,
    //    96 KB dyn LDS request -> 1 block/CU, 256 blocks)
    gemm_bt<<<256, 512, 98304, stream>>>(attnb, wprojT, b_proj, out, M_ROWS, C_DIM, C_DIM);
}